// Round 4
// baseline (375.628 us; speedup 1.0000x reference)
//
#include <hip/hip_runtime.h>
#include <hip/hip_bf16.h>
#include <stdint.h>

#define T_ROWS 131072
#define GCNT   64
#define KDIM   1024
#define NDIM   512
#define BM     256
#define BN     256
#define BK     64
#define KTILES (KDIM / BK)     // 16
#define MT_MAX 640             // upper bound on 256-row tiles (actual ~550)
#define NBLK   (MT_MAX * 2)    // 1280 blocks, divisible by 8 (XCD swizzle)

typedef __attribute__((ext_vector_type(4))) float f32x4;
typedef __attribute__((ext_vector_type(8))) short s16x8;
typedef __attribute__((ext_vector_type(4))) short s16x4;
typedef __attribute__((address_space(3))) unsigned int lds_u32;
typedef const __attribute__((address_space(1))) unsigned int gbl_u32;

static __device__ __forceinline__ short f2bf(float f) {
  __hip_bfloat16 h = __float2bfloat16(f);
  return __builtin_bit_cast(short, h);
}

// ---------------------------------------------------------------------------
// Pre-pass: b [G][K][N] fp32 -> bt: per (g, nt128, kt) 16KB bf16 tile images,
// layout [G][4][16][16384B]. Image byte for B[k][n] (k in [0,64), n in
// [0,128)):  n*128 + (((k>>3) ^ (n&7))<<4) + (k&7)*2   (bank swizzle baked).
// ---------------------------------------------------------------------------
__global__ __launch_bounds__(256) void bt_kernel(const float* __restrict__ b,
                                                 char* __restrict__ bt) {
  __shared__ short lt[64 * 130];
  int bid = blockIdx.x;               // g*64 + nt*16 + kt
  int kt = bid & 15, nt = (bid >> 4) & 3, g = bid >> 6;
  int t = threadIdx.x;
  const float* src = b + ((size_t)(g * KDIM + kt * BK)) * NDIM + nt * 128;
#pragma unroll
  for (int i = 0; i < 32; i++) {
    int idx = i * 256 + t;
    int kk = idx >> 7, nn = idx & 127;
    lt[kk * 130 + nn] = f2bf(src[(size_t)kk * NDIM + nn]);
  }
  __syncthreads();
  char* dst = bt + ((size_t)bid << 14);
#pragma unroll
  for (int j = 0; j < 4; j++) {
    int chunk = j * 256 + t;
    int n = chunk >> 3;
    int slot = (chunk & 7) ^ (n & 7);
    s16x8 v;
#pragma unroll
    for (int i = 0; i < 8; i++) v[i] = lt[(slot * 8 + i) * 130 + n];
    *(s16x8*)(dst + (size_t)chunk * 16) = v;
  }
}

// ---------------------------------------------------------------------------
// 8-phase grouped GEMM with counted vmcnt (T3+T4): 256x256, 8 waves, BK=64.
// Per K-tile kt (computing buf cur = kt&1):
//   ph0: dsA q0 + dsB ks0 | issue B-DMA(kt+1) h0 | bar | 16 MFMA | bar
//   ph1: dsA q0 + dsB ks1 | issue B-DMA(kt+1) h1 | bar | 16 MFMA | bar
//   ph2: dsA q1           | cvt A(kt+1) h0, issue A(kt+2) h0 | bar | MFMA | bar
//   ph3: dsA q1           | cvt A(kt+1) h1, issue A(kt+2) h1 | bar | MFMA | bar
//   ph4: ds_write A(kt+1) | s_waitcnt vmcnt(8) lgkmcnt(0)    | bar
// vmcnt(8) retires the 4 B-DMAs (older) and keeps the 8 A(kt+2) fp32 loads
// (newer) in flight ACROSS the barrier -> the HBM A-stream never drains.
// ---------------------------------------------------------------------------
__global__ __launch_bounds__(512, 2) void gemm8(
    const float* __restrict__ a, const char* __restrict__ bt,
    const int* __restrict__ sizes, const int* __restrict__ offs,
    float* __restrict__ out) {
  __shared__ __align__(16) short lds_a[2][BM * BK];     // 2 x 32 KB
  __shared__ __align__(16) char lds_b[2][BN * BK * 2];  // 2 x 32 KB

  int bid0 = blockIdx.x;
  int bid = (bid0 & 7) * (NBLK / 8) + (bid0 >> 3);  // XCD-chunked swizzle
  int bn = bid & 1;                                 // A-sharing pair adjacent
  int tm = bid >> 1;

  int g = -1, m_loc = 0, base = 0;
#pragma unroll
  for (int i = 0; i < GCNT; i++) {
    int ps = (sizes[i] + 127) & ~127;
    int tg = (ps + 255) >> 8;
    if (tm >= base && tm < base + tg) { g = i; m_loc = (tm - base) << 8; }
    base += tg;
  }
  if (g < 0) return;
  int size = sizes[g], off = offs[g], valid = size - m_loc;

  int t = threadIdx.x, lane = t & 63, wid = t >> 6;
  int wm = wid >> 2, wn = wid & 3, lr = lane & 15, q = lane >> 4;

  // A staging: thread t owns rows i*32 + (t>>4), fp32 cols (t&15)*4..+3
  int r0 = t >> 4, c16 = t & 15;
  int aoff[8];
#pragma unroll
  for (int i = 0; i < 8; i++) {
    int row = off + m_loc + i * 32 + r0;
    if (row >= T_ROWS) row = T_ROWS - 1;  // junk rows masked at store
    aoff[i] = row * KDIM + c16 * 4;
  }
  int a_wbyte = r0 * 128 + (((c16 >> 1) ^ (r0 & 7)) << 4) + (c16 & 1) * 8;

  const char* btbase = bt + ((size_t)g << 20);

  f32x4 acc[8][4];
#pragma unroll
  for (int i = 0; i < 8; i++)
#pragma unroll
    for (int j = 0; j < 4; j++) acc[i][j] = (f32x4){0.f, 0.f, 0.f, 0.f};
  f32x4 va[8];      // single fp32 bank: holds A(kt+1) then refilled A(kt+2)
  s16x4 pk[8];      // converted bf16 staging for A(kt+1)
  s16x8 af[4], bf0[4], bf1[4];

  auto issueA = [&](int kt, int h) {
#pragma unroll
    for (int i = 0; i < 4; i++)
      va[h * 4 + i] = *(const f32x4*)(a + aoff[h * 4 + i] + kt * BK);
  };
  auto cvtHalf = [&](int h) {  // compiler auto-inserts counted vmcnt for va
#pragma unroll
    for (int i = 0; i < 4; i++) {
      s16x4 v;
#pragma unroll
      for (int e = 0; e < 4; e++) v[e] = f2bf(va[h * 4 + i][e]);
      pk[h * 4 + i] = v;
    }
  };
  auto writeA = [&](int c) {
    char* db = (char*)lds_a[c] + a_wbyte;
#pragma unroll
    for (int i = 0; i < 8; i++) *(s16x4*)(db + i * 4096) = pk[i];
  };
  auto issueB = [&](int kt, int c, int h) {
#pragma unroll
    for (int i = 0; i < 2; i++) {
      int wc = wid * 4 + h * 2 + i;          // wave-uniform chunk id
      int sub = wc >> 4;
      int cc = (wc & 15) * 64 + lane;
      const char* gsrc =
          btbase + (((size_t)((bn * 2 + sub) * 16 + kt)) << 14) + cc * 16;
      __builtin_amdgcn_global_load_lds(
          (gbl_u32*)gsrc, (lds_u32*)((char*)lds_b[c] + wc * 1024), 16, 0, 0);
    }
  };
  auto dsA = [&](int c, int half, int ks) {
#pragma unroll
    for (int i = 0; i < 4; i++) {
      int row = wm * 128 + (half * 4 + i) * 16 + lr;
      int slot = (ks * 4 + q) ^ (row & 7);
      af[i] = *(const s16x8*)((const char*)lds_a[c] + row * 128 + slot * 16);
    }
  };
  auto dsB = [&](int c, int ks, s16x8* bf) {
#pragma unroll
    for (int fn = 0; fn < 4; fn++) {
      int n = wn * 64 + fn * 16 + lr;
      int slot = (ks * 4 + q) ^ (n & 7);
      bf[fn] = *(const s16x8*)((const char*)lds_b[c] + (n >> 7) * 16384 +
                               (n & 127) * 128 + slot * 16);
    }
  };
  auto bar = [&]() {
    __builtin_amdgcn_s_barrier();
    __builtin_amdgcn_sched_barrier(0);
  };
  auto mfmaQ = [&](const s16x8* bf, int fmb) {
    __builtin_amdgcn_s_setprio(1);
#pragma unroll
    for (int fm = 0; fm < 4; fm++)
#pragma unroll
      for (int fn = 0; fn < 4; fn++)
        acc[fmb + fm][fn] = __builtin_amdgcn_mfma_f32_16x16x32_bf16(
            af[fm], bf[fn], acc[fmb + fm][fn], 0, 0, 0);
    __builtin_amdgcn_s_setprio(0);
  };

  // prologue: A(0) -> cvt -> LDS buf0; DMA B(0) -> buf0; A(1) in flight.
  issueA(0, 0);
  issueA(0, 1);
  cvtHalf(0);
  cvtHalf(1);
  writeA(0);
  issueB(0, 0, 0);
  issueB(0, 0, 1);   // 4 DMA (older)
  issueA(1, 0);
  issueA(1, 1);      // 8 A-loads (newer), stay in flight
  asm volatile("s_waitcnt vmcnt(8) lgkmcnt(0)" ::: "memory");
  __builtin_amdgcn_sched_barrier(0);
  bar();

  for (int kt = 0; kt < KTILES; kt++) {
    int cur = kt & 1, nxt = cur ^ 1;
    bool moreB = (kt + 1 < KTILES);
    bool moreA = (kt + 2 < KTILES);
    // ph0
    dsA(cur, 0, 0);
    dsB(cur, 0, bf0);
    if (moreB) issueB(kt + 1, nxt, 0);
    bar();
    mfmaQ(bf0, 0);
    bar();
    // ph1
    dsA(cur, 0, 1);
    dsB(cur, 1, bf1);
    if (moreB) issueB(kt + 1, nxt, 1);
    bar();
    mfmaQ(bf1, 0);
    bar();
    // ph2
    dsA(cur, 1, 0);
    if (moreB) cvtHalf(0);        // consumes A(kt+1) h0 (precise auto-vmcnt)
    if (moreA) issueA(kt + 2, 0); // refill bank h0
    bar();
    mfmaQ(bf0, 4);
    bar();
    // ph3
    dsA(cur, 1, 1);
    if (moreB) cvtHalf(1);
    if (moreA) issueA(kt + 2, 1);
    bar();
    mfmaQ(bf1, 4);
    bar();
    // ph4: commit A(kt+1), retire DMAs only, keep A(kt+2) in flight
    if (moreB) {
      writeA(nxt);
      if (moreA)
        asm volatile("s_waitcnt vmcnt(8) lgkmcnt(0)" ::: "memory");
      else
        asm volatile("s_waitcnt vmcnt(0) lgkmcnt(0)" ::: "memory");
      __builtin_amdgcn_sched_barrier(0);
      bar();
    }
  }

  // epilogue: D frag col = lane&15, row = (lane>>4)*4 + j; masked rows
  size_t orow0 = (size_t)(off + m_loc);
#pragma unroll
  for (int fm = 0; fm < 8; fm++) {
#pragma unroll
    for (int j = 0; j < 4; j++) {
      int rm = wm * 128 + fm * 16 + q * 4 + j;
      if (rm < valid) {
        float* orow = out + (orow0 + rm) * NDIM + bn * BN + wn * 64 + lr;
#pragma unroll
        for (int fn = 0; fn < 4; fn++) orow[fn * 16] = acc[fm][fn][j];
      }
    }
  }
}

// ---------------------------------------------------------------------------
// Fallback (no workspace): round-2 2-phase kernel, B transposed in-kernel.
// ---------------------------------------------------------------------------
__global__ __launch_bounds__(512, 2) void gemm_fb(
    const float* __restrict__ a, const float* __restrict__ b,
    const int* __restrict__ sizes, const int* __restrict__ offs,
    float* __restrict__ out) {
  __shared__ __align__(16) short lds_a[2][BM * BK];
  __shared__ __align__(16) char lds_b[2][BN * BK * 2];

  int bid0 = blockIdx.x;
  int bid = (bid0 & 7) * (NBLK / 8) + (bid0 >> 3);
  int bn = bid & 1;
  int tm = bid >> 1;

  int g = -1, m_loc = 0, base = 0;
#pragma unroll
  for (int i = 0; i < GCNT; i++) {
    int ps = (sizes[i] + 127) & ~127;
    int tg = (ps + 255) >> 8;
    if (tm >= base && tm < base + tg) { g = i; m_loc = (tm - base) << 8; }
    base += tg;
  }
  if (g < 0) return;
  int size = sizes[g], off = offs[g], valid = size - m_loc;

  int t = threadIdx.x, lane = t & 63, wid = t >> 6;
  int wm = wid >> 2, wn = wid & 3, lr = lane & 15, q = lane >> 4;

  int r0 = t >> 4, c16 = t & 15;
  int aoff[8];
#pragma unroll
  for (int i = 0; i < 8; i++) {
    int row = off + m_loc + i * 32 + r0;
    if (row >= T_ROWS) row = T_ROWS - 1;
    aoff[i] = row * KDIM + c16 * 4;
  }
  int a_wbyte = r0 * 128 + (((c16 >> 1) ^ (r0 & 7)) << 4) + (c16 & 1) * 8;
  int fb_n = t >> 1, fb_kh = (t & 1) * 32;

  f32x4 acc[8][4];
#pragma unroll
  for (int i = 0; i < 8; i++)
#pragma unroll
    for (int j = 0; j < 4; j++) acc[i][j] = (f32x4){0.f, 0.f, 0.f, 0.f};
  f32x4 va[8];

  auto loadA = [&](int kt) {
#pragma unroll
    for (int i = 0; i < 8; i++) va[i] = *(const f32x4*)(a + aoff[i] + kt * BK);
  };
  auto writeA = [&](int c) {
    char* db = (char*)lds_a[c] + a_wbyte;
#pragma unroll
    for (int i = 0; i < 8; i++) {
      s16x4 v;
#pragma unroll
      for (int e = 0; e < 4; e++) v[e] = f2bf(va[i][e]);
      *(s16x4*)(db + i * 4096) = v;
    }
  };
  auto stageB = [&](int kt, int c) {
    const float* p = b + (size_t)g * KDIM * NDIM +
                     (size_t)(kt * BK + fb_kh) * NDIM + bn * BN + fb_n;
    float vals[32];
#pragma unroll
    for (int i = 0; i < 32; i++) vals[i] = p[(size_t)i * NDIM];
    int nn = fb_n & 127;
    char* lb = (char*)lds_b[c] + (fb_n >> 7) * 16384 + nn * 128;
#pragma unroll
    for (int i8 = 0; i8 < 4; i8++) {
      int slot = (fb_kh >> 3) + i8;
      s16x8 v;
#pragma unroll
      for (int e = 0; e < 8; e++) v[e] = f2bf(vals[i8 * 8 + e]);
      *(s16x8*)(lb + (((slot ^ (nn & 7))) << 4)) = v;
    }
  };
  auto compute = [&](int c) {
#pragma unroll
    for (int ks = 0; ks < 2; ks++) {
      s16x8 af[8], bfr[4];
#pragma unroll
      for (int fm = 0; fm < 8; fm++) {
        int row = wm * 128 + fm * 16 + lr;
        int slot = (ks * 4 + q) ^ (row & 7);
        af[fm] = *(const s16x8*)((const char*)lds_a[c] + row * 128 + slot * 16);
      }
#pragma unroll
      for (int fn = 0; fn < 4; fn++) {
        int n = wn * 64 + fn * 16 + lr;
        int slot = (ks * 4 + q) ^ (n & 7);
        bfr[fn] = *(const s16x8*)((const char*)lds_b[c] + (n >> 7) * 16384 +
                                  (n & 127) * 128 + slot * 16);
      }
#pragma unroll
      for (int fm = 0; fm < 8; fm++)
#pragma unroll
        for (int fn = 0; fn < 4; fn++)
          acc[fm][fn] = __builtin_amdgcn_mfma_f32_16x16x32_bf16(
              af[fm], bfr[fn], acc[fm][fn], 0, 0, 0);
    }
  };

  loadA(0);
  stageB(0, 0);
  writeA(0);
  __syncthreads();
  int cur = 0;
  for (int kt = 0; kt < KTILES; kt++) {
    if (kt + 1 < KTILES) loadA(kt + 1);
    compute(cur);
    if (kt + 1 < KTILES) {
      stageB(kt + 1, cur ^ 1);
      writeA(cur ^ 1);
      __syncthreads();
      cur ^= 1;
    }
  }
  size_t orow0 = (size_t)(off + m_loc);
#pragma unroll
  for (int fm = 0; fm < 8; fm++) {
#pragma unroll
    for (int j = 0; j < 4; j++) {
      int rm = wm * 128 + fm * 16 + q * 4 + j;
      if (rm < valid) {
        float* orow = out + (orow0 + rm) * NDIM + bn * BN + wn * 64 + lr;
#pragma unroll
        for (int fn = 0; fn < 4; fn++) orow[fn * 16] = acc[fm][fn][j];
      }
    }
  }
}

extern "C" void kernel_launch(void* const* d_in, const int* in_sizes, int n_in,
                              void* d_out, int out_size, void* d_ws,
                              size_t ws_size, hipStream_t stream) {
  const float* a = (const float*)d_in[0];
  const float* b = (const float*)d_in[1];
  const int* sizes = (const int*)d_in[2];
  const int* offs = (const int*)d_in[3];
  float* out = (float*)d_out;

  const size_t bt_bytes = (size_t)GCNT * KDIM * NDIM * 2;  // 64 MB
  if (ws_size >= bt_bytes) {
    bt_kernel<<<GCNT * 64, 256, 0, stream>>>(b, (char*)d_ws);
    gemm8<<<NBLK, 512, 0, stream>>>(a, (const char*)d_ws, sizes, offs, out);
  } else {
    gemm_fb<<<NBLK, 512, 0, stream>>>(a, b, sizes, offs, out);
  }
}

// Round 5
// 373.916 us; speedup vs baseline: 1.0046x; 1.0046x over previous
//
#include <hip/hip_runtime.h>
#include <hip/hip_bf16.h>
#include <stdint.h>

#define T_ROWS 131072
#define GCNT   64
#define KDIM   1024
#define NDIM   512
#define BM     256
#define BN     256
#define BK     64
#define KTILES (KDIM / BK)     // 16
#define MT_MAX 640             // upper bound on 256-row tiles (actual ~550)
#define NBLK   (MT_MAX * 2)    // 1280 blocks, divisible by 8 (XCD swizzle)

typedef __attribute__((ext_vector_type(4))) float f32x4;
typedef __attribute__((ext_vector_type(8))) short s16x8;
typedef __attribute__((ext_vector_type(4))) short s16x4;
typedef __attribute__((address_space(3))) unsigned int lds_u32;
typedef const __attribute__((address_space(1))) unsigned int gbl_u32;

static __device__ __forceinline__ short f2bf(float f) {
  __hip_bfloat16 h = __float2bfloat16(f);
  return __builtin_bit_cast(short, h);
}

// ---------------------------------------------------------------------------
// Pre-pass: b [G][K][N] fp32 -> bt: per (g, nt128, kt) 16KB bf16 tile images,
// layout [G][4][16][16384B]. Image byte for B[k][n] (k in [0,64), n in
// [0,128)):  n*128 + (((k>>3) ^ (n&7))<<4) + (k&7)*2   (bank swizzle baked).
// ---------------------------------------------------------------------------
__global__ __launch_bounds__(256) void bt_kernel(const float* __restrict__ b,
                                                 char* __restrict__ bt) {
  __shared__ short lt[64 * 130];
  int bid = blockIdx.x;               // g*64 + nt*16 + kt
  int kt = bid & 15, nt = (bid >> 4) & 3, g = bid >> 6;
  int t = threadIdx.x;
  const float* src = b + ((size_t)(g * KDIM + kt * BK)) * NDIM + nt * 128;
#pragma unroll
  for (int i = 0; i < 32; i++) {
    int idx = i * 256 + t;
    int kk = idx >> 7, nn = idx & 127;
    lt[kk * 130 + nn] = f2bf(src[(size_t)kk * NDIM + nn]);
  }
  __syncthreads();
  char* dst = bt + ((size_t)bid << 14);
#pragma unroll
  for (int j = 0; j < 4; j++) {
    int chunk = j * 256 + t;
    int n = chunk >> 3;
    int slot = (chunk & 7) ^ (n & 7);
    s16x8 v;
#pragma unroll
    for (int i = 0; i < 8; i++) v[i] = lt[(slot * 8 + i) * 130 + n];
    *(s16x8*)(dst + (size_t)chunk * 16) = v;
  }
}

// ---------------------------------------------------------------------------
// 8-phase grouped GEMM, ONE barrier per phase (m201-style interleave):
//   phase p: {ds_reads from cur | prefetch issues into nxt | cvt}
//            -> sched_barrier -> s_barrier -> (counted lgkm by compiler)
//            -> setprio(1) 16 MFMA setprio(0)
// so phase p+1's LDS reads overlap phase p's MFMA across waves.
// Tile boundary (ph4): ds_write A(kt+1) -> vmcnt(8) [retire the 4 B-DMAs,
// keep the 8 A(kt+2) fp32 loads in flight] + lgkmcnt(0) -> barrier.
// ---------------------------------------------------------------------------
__global__ __launch_bounds__(512, 2) void gemm8(
    const float* __restrict__ a, const char* __restrict__ bt,
    const int* __restrict__ sizes, const int* __restrict__ offs,
    float* __restrict__ out) {
  __shared__ __align__(16) short lds_a[2][BM * BK];     // 2 x 32 KB
  __shared__ __align__(16) char lds_b[2][BN * BK * 2];  // 2 x 32 KB

  int bid0 = blockIdx.x;
  int bid = (bid0 & 7) * (NBLK / 8) + (bid0 >> 3);  // XCD-chunked swizzle
  int bn = bid & 1;                                 // A-sharing pair adjacent
  int tm = bid >> 1;

  int g = -1, m_loc = 0, base = 0;
#pragma unroll
  for (int i = 0; i < GCNT; i++) {
    int ps = (sizes[i] + 127) & ~127;
    int tg = (ps + 255) >> 8;
    if (tm >= base && tm < base + tg) { g = i; m_loc = (tm - base) << 8; }
    base += tg;
  }
  if (g < 0) return;
  int size = sizes[g], off = offs[g], valid = size - m_loc;

  int t = threadIdx.x, lane = t & 63, wid = t >> 6;
  int wm = wid >> 2, wn = wid & 3, lr = lane & 15, q = lane >> 4;

  // A staging: thread t owns rows i*32 + (t>>4), fp32 cols (t&15)*4..+3
  int r0 = t >> 4, c16 = t & 15;
  int aoff[8];
#pragma unroll
  for (int i = 0; i < 8; i++) {
    int row = off + m_loc + i * 32 + r0;
    if (row >= T_ROWS) row = T_ROWS - 1;  // junk rows masked at store
    aoff[i] = row * KDIM + c16 * 4;
  }
  int a_wbyte = r0 * 128 + (((c16 >> 1) ^ (r0 & 7)) << 4) + (c16 & 1) * 8;

  const char* btbase = bt + ((size_t)g << 20);

  f32x4 acc[8][4];
#pragma unroll
  for (int i = 0; i < 8; i++)
#pragma unroll
    for (int j = 0; j < 4; j++) acc[i][j] = (f32x4){0.f, 0.f, 0.f, 0.f};
  f32x4 va[8];      // fp32 bank: holds A(kt+1), refilled with A(kt+2)
  s16x4 pk[8];      // converted bf16 staging for A(kt+1)
  s16x8 af[4], bf0[4], bf1[4];

  auto issueA = [&](int kt, int h) {
#pragma unroll
    for (int i = 0; i < 4; i++)
      va[h * 4 + i] = *(const f32x4*)(a + aoff[h * 4 + i] + kt * BK);
  };
  auto cvtHalf = [&](int h) {  // compiler inserts counted vmcnt for va
#pragma unroll
    for (int i = 0; i < 4; i++) {
      s16x4 v;
#pragma unroll
      for (int e = 0; e < 4; e++) v[e] = f2bf(va[h * 4 + i][e]);
      pk[h * 4 + i] = v;
    }
  };
  auto writeA = [&](int c) {
    char* db = (char*)lds_a[c] + a_wbyte;
#pragma unroll
    for (int i = 0; i < 8; i++) *(s16x4*)(db + i * 4096) = pk[i];
  };
  auto issueB = [&](int kt, int c, int h) {
#pragma unroll
    for (int i = 0; i < 2; i++) {
      int wc = wid * 4 + h * 2 + i;          // wave-uniform chunk id
      int sub = wc >> 4;
      int cc = (wc & 15) * 64 + lane;
      const char* gsrc =
          btbase + (((size_t)((bn * 2 + sub) * 16 + kt)) << 14) + cc * 16;
      __builtin_amdgcn_global_load_lds(
          (gbl_u32*)gsrc, (lds_u32*)((char*)lds_b[c] + wc * 1024), 16, 0, 0);
    }
  };
  auto dsA = [&](int c, int half, int ks) {
#pragma unroll
    for (int i = 0; i < 4; i++) {
      int row = wm * 128 + (half * 4 + i) * 16 + lr;
      int slot = (ks * 4 + q) ^ (row & 7);
      af[i] = *(const s16x8*)((const char*)lds_a[c] + row * 128 + slot * 16);
    }
  };
  auto dsB = [&](int c, int ks, s16x8* bf) {
#pragma unroll
    for (int fn = 0; fn < 4; fn++) {
      int n = wn * 64 + fn * 16 + lr;
      int slot = (ks * 4 + q) ^ (n & 7);
      bf[fn] = *(const s16x8*)((const char*)lds_b[c] + (n >> 7) * 16384 +
                               (n & 127) * 128 + slot * 16);
    }
  };
  auto phase_bar = [&]() {
    __builtin_amdgcn_sched_barrier(0);   // pin reads/issues before barrier
    __builtin_amdgcn_s_barrier();
  };
  auto mfmaQ = [&](const s16x8* bf, int fmb) {
    __builtin_amdgcn_s_setprio(1);
#pragma unroll
    for (int fm = 0; fm < 4; fm++)
#pragma unroll
      for (int fn = 0; fn < 4; fn++)
        acc[fmb + fm][fn] = __builtin_amdgcn_mfma_f32_16x16x32_bf16(
            af[fm], bf[fn], acc[fmb + fm][fn], 0, 0, 0);
    __builtin_amdgcn_s_setprio(0);
    __builtin_amdgcn_sched_barrier(0);   // pin MFMA before next phase reads
  };

  // prologue: A(0) -> cvt -> LDS buf0; DMA B(0) -> buf0; A(1) in flight.
  issueA(0, 0);
  issueA(0, 1);
  cvtHalf(0);
  cvtHalf(1);
  writeA(0);
  issueB(0, 0, 0);
  issueB(0, 0, 1);   // 4 DMA (older)
  issueA(1, 0);
  issueA(1, 1);      // 8 A-loads (newer), stay in flight
  asm volatile("s_waitcnt vmcnt(8) lgkmcnt(0)" ::: "memory");
  __builtin_amdgcn_sched_barrier(0);
  __builtin_amdgcn_s_barrier();

  for (int kt = 0; kt < KTILES; kt++) {
    int cur = kt & 1, nxt = cur ^ 1;
    bool moreB = (kt + 1 < KTILES);
    bool moreA = (kt + 2 < KTILES);
    // ph0: reads Q0 + bf(ks0); issue B-DMA(kt+1) h0
    dsA(cur, 0, 0);
    dsB(cur, 0, bf0);
    if (moreB) issueB(kt + 1, nxt, 0);
    phase_bar();
    mfmaQ(bf0, 0);
    // ph1: reads Q1 + bf(ks1); issue B-DMA(kt+1) h1
    dsA(cur, 0, 1);
    dsB(cur, 1, bf1);
    if (moreB) issueB(kt + 1, nxt, 1);
    phase_bar();
    mfmaQ(bf1, 0);
    // ph2: reads Q2; cvt A(kt+1) h0 (counted auto-vmcnt); issue A(kt+2) h0
    dsA(cur, 1, 0);
    if (moreB) cvtHalf(0);
    if (moreA) issueA(kt + 2, 0);
    phase_bar();
    mfmaQ(bf0, 4);
    // ph3: reads Q3; cvt A(kt+1) h1; issue A(kt+2) h1
    dsA(cur, 1, 1);
    if (moreB) cvtHalf(1);
    if (moreA) issueA(kt + 2, 1);
    phase_bar();
    mfmaQ(bf1, 4);
    // ph4 (tile boundary): publish A ds_writes + B DMAs; keep A(kt+2) flying
    if (moreB) {
      writeA(nxt);
      if (moreA)
        asm volatile("s_waitcnt vmcnt(8) lgkmcnt(0)" ::: "memory");
      else
        asm volatile("s_waitcnt vmcnt(0) lgkmcnt(0)" ::: "memory");
      __builtin_amdgcn_sched_barrier(0);
      __builtin_amdgcn_s_barrier();
    }
  }

  // epilogue: D frag col = lane&15, row = (lane>>4)*4 + j; masked rows
  size_t orow0 = (size_t)(off + m_loc);
#pragma unroll
  for (int fm = 0; fm < 8; fm++) {
#pragma unroll
    for (int j = 0; j < 4; j++) {
      int rm = wm * 128 + fm * 16 + q * 4 + j;
      if (rm < valid) {
        float* orow = out + (orow0 + rm) * NDIM + bn * BN + wn * 64 + lr;
#pragma unroll
        for (int fn = 0; fn < 4; fn++) orow[fn * 16] = acc[fm][fn][j];
      }
    }
  }
}

// ---------------------------------------------------------------------------
// Fallback (no workspace): round-2 2-phase kernel, B transposed in-kernel.
// ---------------------------------------------------------------------------
__global__ __launch_bounds__(512, 2) void gemm_fb(
    const float* __restrict__ a, const float* __restrict__ b,
    const int* __restrict__ sizes, const int* __restrict__ offs,
    float* __restrict__ out) {
  __shared__ __align__(16) short lds_a[2][BM * BK];
  __shared__ __align__(16) char lds_b[2][BN * BK * 2];

  int bid0 = blockIdx.x;
  int bid = (bid0 & 7) * (NBLK / 8) + (bid0 >> 3);
  int bn = bid & 1;
  int tm = bid >> 1;

  int g = -1, m_loc = 0, base = 0;
#pragma unroll
  for (int i = 0; i < GCNT; i++) {
    int ps = (sizes[i] + 127) & ~127;
    int tg = (ps + 255) >> 8;
    if (tm >= base && tm < base + tg) { g = i; m_loc = (tm - base) << 8; }
    base += tg;
  }
  if (g < 0) return;
  int size = sizes[g], off = offs[g], valid = size - m_loc;

  int t = threadIdx.x, lane = t & 63, wid = t >> 6;
  int wm = wid >> 2, wn = wid & 3, lr = lane & 15, q = lane >> 4;

  int r0 = t >> 4, c16 = t & 15;
  int aoff[8];
#pragma unroll
  for (int i = 0; i < 8; i++) {
    int row = off + m_loc + i * 32 + r0;
    if (row >= T_ROWS) row = T_ROWS - 1;
    aoff[i] = row * KDIM + c16 * 4;
  }
  int a_wbyte = r0 * 128 + (((c16 >> 1) ^ (r0 & 7)) << 4) + (c16 & 1) * 8;
  int fb_n = t >> 1, fb_kh = (t & 1) * 32;

  f32x4 acc[8][4];
#pragma unroll
  for (int i = 0; i < 8; i++)
#pragma unroll
    for (int j = 0; j < 4; j++) acc[i][j] = (f32x4){0.f, 0.f, 0.f, 0.f};
  f32x4 va[8];

  auto loadA = [&](int kt) {
#pragma unroll
    for (int i = 0; i < 8; i++) va[i] = *(const f32x4*)(a + aoff[i] + kt * BK);
  };
  auto writeA = [&](int c) {
    char* db = (char*)lds_a[c] + a_wbyte;
#pragma unroll
    for (int i = 0; i < 8; i++) {
      s16x4 v;
#pragma unroll
      for (int e = 0; e < 4; e++) v[e] = f2bf(va[i][e]);
      *(s16x4*)(db + i * 4096) = v;
    }
  };
  auto stageB = [&](int kt, int c) {
    const float* p = b + (size_t)g * KDIM * NDIM +
                     (size_t)(kt * BK + fb_kh) * NDIM + bn * BN + fb_n;
    float vals[32];
#pragma unroll
    for (int i = 0; i < 32; i++) vals[i] = p[(size_t)i * NDIM];
    int nn = fb_n & 127;
    char* lb = (char*)lds_b[c] + (fb_n >> 7) * 16384 + nn * 128;
#pragma unroll
    for (int i8 = 0; i8 < 4; i8++) {
      int slot = (fb_kh >> 3) + i8;
      s16x8 v;
#pragma unroll
      for (int e = 0; e < 8; e++) v[e] = f2bf(vals[i8 * 8 + e]);
      *(s16x8*)(lb + (((slot ^ (nn & 7))) << 4)) = v;
    }
  };
  auto compute = [&](int c) {
#pragma unroll
    for (int ks = 0; ks < 2; ks++) {
      s16x8 af[8], bfr[4];
#pragma unroll
      for (int fm = 0; fm < 8; fm++) {
        int row = wm * 128 + fm * 16 + lr;
        int slot = (ks * 4 + q) ^ (row & 7);
        af[fm] = *(const s16x8*)((const char*)lds_a[c] + row * 128 + slot * 16);
      }
#pragma unroll
      for (int fn = 0; fn < 4; fn++) {
        int n = wn * 64 + fn * 16 + lr;
        int slot = (ks * 4 + q) ^ (n & 7);
        bfr[fn] = *(const s16x8*)((const char*)lds_b[c] + (n >> 7) * 16384 +
                                  (n & 127) * 128 + slot * 16);
      }
#pragma unroll
      for (int fm = 0; fm < 8; fm++)
#pragma unroll
        for (int fn = 0; fn < 4; fn++)
          acc[fm][fn] = __builtin_amdgcn_mfma_f32_16x16x32_bf16(
              af[fm], bfr[fn], acc[fm][fn], 0, 0, 0);
    }
  };

  loadA(0);
  stageB(0, 0);
  writeA(0);
  __syncthreads();
  int cur = 0;
  for (int kt = 0; kt < KTILES; kt++) {
    if (kt + 1 < KTILES) loadA(kt + 1);
    compute(cur);
    if (kt + 1 < KTILES) {
      stageB(kt + 1, cur ^ 1);
      writeA(cur ^ 1);
      __syncthreads();
      cur ^= 1;
    }
  }
  size_t orow0 = (size_t)(off + m_loc);
#pragma unroll
  for (int fm = 0; fm < 8; fm++) {
#pragma unroll
    for (int j = 0; j < 4; j++) {
      int rm = wm * 128 + fm * 16 + q * 4 + j;
      if (rm < valid) {
        float* orow = out + (orow0 + rm) * NDIM + bn * BN + wn * 64 + lr;
#pragma unroll
        for (int fn = 0; fn < 4; fn++) orow[fn * 16] = acc[fm][fn][j];
      }
    }
  }
}

extern "C" void kernel_launch(void* const* d_in, const int* in_sizes, int n_in,
                              void* d_out, int out_size, void* d_ws,
                              size_t ws_size, hipStream_t stream) {
  const float* a = (const float*)d_in[0];
  const float* b = (const float*)d_in[1];
  const int* sizes = (const int*)d_in[2];
  const int* offs = (const int*)d_in[3];
  float* out = (float*)d_out;

  const size_t bt_bytes = (size_t)GCNT * KDIM * NDIM * 2;  // 64 MB
  if (ws_size >= bt_bytes) {
    bt_kernel<<<GCNT * 64, 256, 0, stream>>>(b, (char*)d_ws);
    gemm8<<<NBLK, 512, 0, stream>>>(a, (const char*)d_ws, sizes, offs, out);
  } else {
    gemm_fb<<<NBLK, 512, 0, stream>>>(a, b, sizes, offs, out);
  }
}